// Round 1
// baseline (41950.168 us; speedup 1.0000x reference)
//
#include <hip/hip_runtime.h>
#include <math.h>

// MoE forward, MI355X. Round 1: correct fp32 baseline with sparse routing.
// B=32768 D=1200 E=16 H=1024 O=1 K=4.
// d_out = [ y (32768 f32) | loss (1 f32) ]
//
// ws layout:
//   [0         , 2 MiB)  bucket_row  : int  [E][B]
//   [2 MiB     , 4 MiB)  bucket_gate : f32  [E][B]
//   [4 MiB +0  )         cnt         : int  [E]
//   [4 MiB +64 )         importance  : f32  [E]
//   [4 MiB +128)         load        : int  [E]

#define B_SZ   32768
#define D_SZ   1200
#define E_SZ   16
#define H_SZ   1024
#define LN_EPS 1e-5f
#define BM     64
#define KB     16

// ---------------------------------------------------------------- gating ----
__global__ __launch_bounds__(256)
void gate_kernel(const float* __restrict__ x, const float* __restrict__ wg,
                 int* __restrict__ bucket_row, float* __restrict__ bucket_gate,
                 int* __restrict__ cnt, float* __restrict__ importance,
                 int* __restrict__ load_cnt)
{
    __shared__ float s_imp[E_SZ];
    __shared__ int   s_load[E_SZ];
    if (threadIdx.x < E_SZ) { s_imp[threadIdx.x] = 0.f; s_load[threadIdx.x] = 0; }
    __syncthreads();

    const int lane  = threadIdx.x & 63;
    const int gwave = (int)((blockIdx.x * blockDim.x + threadIdx.x) >> 6);
    const int nwave = (int)((gridDim.x * blockDim.x) >> 6);

    for (int row = gwave; row < B_SZ; row += nwave) {
        float acc[E_SZ];
#pragma unroll
        for (int e = 0; e < E_SZ; ++e) acc[e] = 0.f;

        const float* xr = x + (size_t)row * D_SZ;
        for (int d = lane; d < D_SZ; d += 64) {
            const float xv = xr[d];
            const float4* w4 = (const float4*)(wg + (size_t)d * E_SZ);
            const float4 a = w4[0], b = w4[1], c = w4[2], dd = w4[3];
            acc[0]  += xv * a.x;  acc[1]  += xv * a.y;
            acc[2]  += xv * a.z;  acc[3]  += xv * a.w;
            acc[4]  += xv * b.x;  acc[5]  += xv * b.y;
            acc[6]  += xv * b.z;  acc[7]  += xv * b.w;
            acc[8]  += xv * c.x;  acc[9]  += xv * c.y;
            acc[10] += xv * c.z;  acc[11] += xv * c.w;
            acc[12] += xv * dd.x; acc[13] += xv * dd.y;
            acc[14] += xv * dd.z; acc[15] += xv * dd.w;
        }
#pragma unroll
        for (int e = 0; e < E_SZ; ++e) {
            float v = acc[e];
            v += __shfl_xor(v, 1);  v += __shfl_xor(v, 2);
            v += __shfl_xor(v, 4);  v += __shfl_xor(v, 8);
            v += __shfl_xor(v, 16); v += __shfl_xor(v, 32);
            acc[e] = v;
        }
        if (lane == 0) {
            float mx = acc[0];
#pragma unroll
            for (int e = 1; e < E_SZ; ++e) mx = fmaxf(mx, acc[e]);
            float p[E_SZ]; float s = 0.f;
#pragma unroll
            for (int e = 0; e < E_SZ; ++e) { p[e] = expf(acc[e] - mx); s += p[e]; }
            const float inv = 1.f / s;

            // top-4 (strict > scan == jax top_k lowest-index tie-break)
            unsigned msk = 0; int idx[4]; float val[4]; float gsum = 0.f;
#pragma unroll
            for (int tsel = 0; tsel < 4; ++tsel) {
                float bv = -1.f; int bi = 0;
#pragma unroll
                for (int e = 0; e < E_SZ; ++e) {
                    const bool ok = !((msk >> e) & 1u) && (p[e] > bv);
                    bv = ok ? p[e] : bv; bi = ok ? e : bi;
                }
                msk |= 1u << bi;
                idx[tsel] = bi; val[tsel] = bv * inv; gsum += bv * inv;
            }
            const float denom = gsum + 1e-6f;
#pragma unroll
            for (int tsel = 0; tsel < 4; ++tsel) {
                const float g = val[tsel] / denom;
                const int e = idx[tsel];
                atomicAdd(&s_imp[e], g);
                atomicAdd(&s_load[e], 1);
                const int pos = atomicAdd(&cnt[e], 1);
                bucket_row[e * B_SZ + pos]  = row;
                bucket_gate[e * B_SZ + pos] = g;
            }
        }
    }
    __syncthreads();
    if (threadIdx.x < E_SZ) {
        atomicAdd(&importance[threadIdx.x], s_imp[threadIdx.x]);
        atomicAdd(&load_cnt[threadIdx.x], s_load[threadIdx.x]);
    }
}

// ------------------------------------------------------------------ loss ----
__global__ void loss_kernel(const float* __restrict__ imp,
                            const int* __restrict__ load_cnt,
                            float* __restrict__ loss_out)
{
    if (threadIdx.x == 0 && blockIdx.x == 0) {
        float mi = 0.f, ml = 0.f;
        for (int e = 0; e < E_SZ; ++e) { mi += imp[e]; ml += (float)load_cnt[e]; }
        mi *= (1.f / E_SZ); ml *= (1.f / E_SZ);
        float vi = 0.f, vl = 0.f;
        for (int e = 0; e < E_SZ; ++e) {
            const float di = imp[e] - mi;            vi += di * di;
            const float dl = (float)load_cnt[e] - ml; vl += dl * dl;
        }
        vi *= (1.f / (E_SZ - 1)); vl *= (1.f / (E_SZ - 1));
        *loss_out = 0.5f * (vi / (mi * mi + 1e-10f) + vl / (ml * ml + 1e-10f));
    }
}

// --------------------------------------------------- grouped expert pass ----
// grid (B/BM, E), 1024 threads. Block = 64 gathered rows x full H=1024.
// thread t: row-group tr=t>>7 (8 rows), cols c0=(t&127)*4 -> {c0..c0+3, c0+512..c0+515}
__global__ __launch_bounds__(1024)
void expert_kernel(const float* __restrict__ x, const float* __restrict__ W1,
                   const float* __restrict__ b1, const float* __restrict__ gamma,
                   const float* __restrict__ beta, const float* __restrict__ W2,
                   const float* __restrict__ b2,
                   const int* __restrict__ bucket_row,
                   const float* __restrict__ bucket_gate,
                   const int* __restrict__ cnt, float* __restrict__ y)
{
    const int e   = blockIdx.y;
    const int n_e = cnt[e];
    const int r0  = blockIdx.x * BM;
    if (r0 >= n_e) return;

    __shared__ float xs[BM][KB];        // 4 KiB
    __shared__ float wsm[KB][H_SZ];     // 64 KiB
    __shared__ int   srow[BM];
    __shared__ float sgate[BM];
    __shared__ float red[16][8][2];     // 1 KiB cross-wave reduce

    const int t  = threadIdx.x;
    const int tr = t >> 7;
    const int tc = t & 127;
    const int c0 = tc * 4;

    if (t < BM) {
        const int i = r0 + t;
        srow[t]  = (i < n_e) ? bucket_row[e * B_SZ + i] : -1;
        sgate[t] = (i < n_e) ? bucket_gate[e * B_SZ + i] : 0.f;
    }
    __syncthreads();

    float acc[8][8];
#pragma unroll
    for (int r = 0; r < 8; ++r)
#pragma unroll
        for (int j = 0; j < 8; ++j) acc[r][j] = 0.f;

    const float* W1e = W1 + (size_t)e * D_SZ * H_SZ;

    const int  xr_ = t >> 4;                 // 0..63 : row to stage
    const int  xk_ = t & 15;                 // 0..15 : k within tile
    const long xrow = (srow[xr_] >= 0) ? (long)srow[xr_] * D_SZ : -1L;
    const int  wk_ = t >> 8;                 // 0..3
    const int  wc_ = (t & 255) * 4;          // 0..1020

    for (int kb = 0; kb < D_SZ; kb += KB) {
        xs[xr_][xk_] = (xrow >= 0L) ? x[xrow + kb + xk_] : 0.f;
#pragma unroll
        for (int kk = 0; kk < KB; kk += 4) {
            const float4 v = *(const float4*)(W1e + (size_t)(kb + wk_ + kk) * H_SZ + wc_);
            *(float4*)&wsm[wk_ + kk][wc_] = v;
        }
        __syncthreads();

#pragma unroll
        for (int k4 = 0; k4 < KB; k4 += 4) {
            float wv[4][8];
#pragma unroll
            for (int kk = 0; kk < 4; ++kk) {
                *(float4*)&wv[kk][0] = *(const float4*)&wsm[k4 + kk][c0];
                *(float4*)&wv[kk][4] = *(const float4*)&wsm[k4 + kk][c0 + 512];
            }
#pragma unroll
            for (int r = 0; r < 8; ++r) {
                float xv[4];
                *(float4*)xv = *(const float4*)&xs[tr * 8 + r][k4];   // wave-uniform: broadcast
#pragma unroll
                for (int kk = 0; kk < 4; ++kk)
#pragma unroll
                    for (int j = 0; j < 8; ++j)
                        acc[r][j] += xv[kk] * wv[kk][j];
            }
        }
        __syncthreads();
    }

    // ---- + b1, LayerNorm stats ----
    const float* b1e = b1    + (size_t)e * H_SZ;
    const float* gme = gamma + (size_t)e * H_SZ;
    const float* bte = beta  + (size_t)e * H_SZ;
    const float* w2e = W2    + (size_t)e * H_SZ;    // O==1

    {
        const float4 blo = *(const float4*)(b1e + c0);
        const float4 bhi = *(const float4*)(b1e + c0 + 512);
#pragma unroll
        for (int r = 0; r < 8; ++r) {
            acc[r][0] += blo.x; acc[r][1] += blo.y; acc[r][2] += blo.z; acc[r][3] += blo.w;
            acc[r][4] += bhi.x; acc[r][5] += bhi.y; acc[r][6] += bhi.z; acc[r][7] += bhi.w;
        }
    }

    float sred[8], qred[8];
#pragma unroll
    for (int r = 0; r < 8; ++r) {
        float sv = 0.f, qv = 0.f;
#pragma unroll
        for (int j = 0; j < 8; ++j) { sv += acc[r][j]; qv += acc[r][j] * acc[r][j]; }
        sv += __shfl_xor(sv, 1);  qv += __shfl_xor(qv, 1);
        sv += __shfl_xor(sv, 2);  qv += __shfl_xor(qv, 2);
        sv += __shfl_xor(sv, 4);  qv += __shfl_xor(qv, 4);
        sv += __shfl_xor(sv, 8);  qv += __shfl_xor(qv, 8);
        sv += __shfl_xor(sv, 16); qv += __shfl_xor(qv, 16);
        sv += __shfl_xor(sv, 32); qv += __shfl_xor(qv, 32);
        sred[r] = sv; qred[r] = qv;
    }
    const int w = t >> 6;
    if ((t & 63) == 0) {
#pragma unroll
        for (int r = 0; r < 8; ++r) { red[w][r][0] = sred[r]; red[w][r][1] = qred[r]; }
    }
    __syncthreads();

    float mean[8], rstd[8];
#pragma unroll
    for (int r = 0; r < 8; ++r) {
        const float sm = red[2 * tr][r][0] + red[2 * tr + 1][r][0];
        const float qm = red[2 * tr][r][1] + red[2 * tr + 1][r][1];
        mean[r] = sm * (1.f / H_SZ);
        const float var = qm * (1.f / H_SZ) - mean[r] * mean[r];
        rstd[r] = 1.f / sqrtf(var + LN_EPS);
    }
    __syncthreads();   // before reusing red

    // ---- LN + relu + dot(W2) ----
    float gmv[8], btv[8], w2v[8];
    {
        const float4 a0 = *(const float4*)(gme + c0), a1 = *(const float4*)(gme + c0 + 512);
        const float4 b0 = *(const float4*)(bte + c0), b1_ = *(const float4*)(bte + c0 + 512);
        const float4 c0v = *(const float4*)(w2e + c0), c1 = *(const float4*)(w2e + c0 + 512);
        gmv[0]=a0.x; gmv[1]=a0.y; gmv[2]=a0.z; gmv[3]=a0.w; gmv[4]=a1.x; gmv[5]=a1.y; gmv[6]=a1.z; gmv[7]=a1.w;
        btv[0]=b0.x; btv[1]=b0.y; btv[2]=b0.z; btv[3]=b0.w; btv[4]=b1_.x; btv[5]=b1_.y; btv[6]=b1_.z; btv[7]=b1_.w;
        w2v[0]=c0v.x; w2v[1]=c0v.y; w2v[2]=c0v.z; w2v[3]=c0v.w; w2v[4]=c1.x; w2v[5]=c1.y; w2v[6]=c1.z; w2v[7]=c1.w;
    }

    float pr[8];
#pragma unroll
    for (int r = 0; r < 8; ++r) {
        float p = 0.f;
#pragma unroll
        for (int j = 0; j < 8; ++j) {
            float h = (acc[r][j] - mean[r]) * rstd[r] * gmv[j] + btv[j];
            h = fmaxf(h, 0.f);
            p += h * w2v[j];
        }
        p += __shfl_xor(p, 1);  p += __shfl_xor(p, 2);  p += __shfl_xor(p, 4);
        p += __shfl_xor(p, 8);  p += __shfl_xor(p, 16); p += __shfl_xor(p, 32);
        pr[r] = p;
    }
    if ((t & 63) == 0) {
#pragma unroll
        for (int r = 0; r < 8; ++r) red[w][r][0] = pr[r];
    }
    __syncthreads();

    if (tc == 0) {
        const float b2e = b2[e];
#pragma unroll
        for (int r = 0; r < 8; ++r) {
            const int li = tr * 8 + r;
            if (srow[li] >= 0) {
                const float z = red[2 * tr][r][0] + red[2 * tr + 1][r][0] + b2e;
                const float o = 1.f / (1.f + expf(-z));
                atomicAdd(&y[srow[li]], sgate[li] * o);
            }
        }
    }
}

// -------------------------------------------------------------- launcher ----
extern "C" void kernel_launch(void* const* d_in, const int* in_sizes, int n_in,
                              void* d_out, int out_size, void* d_ws, size_t ws_size,
                              hipStream_t stream)
{
    const float* x     = (const float*)d_in[0];
    const float* wg    = (const float*)d_in[1];
    const float* W1    = (const float*)d_in[2];
    const float* b1    = (const float*)d_in[3];
    const float* gamma = (const float*)d_in[4];
    const float* beta  = (const float*)d_in[5];
    const float* W2    = (const float*)d_in[6];
    const float* b2    = (const float*)d_in[7];
    float* y = (float*)d_out;

    char* ws = (char*)d_ws;
    int*   bucket_row  = (int*)ws;
    float* bucket_gate = (float*)(ws + (size_t)E_SZ * B_SZ * 4);
    const size_t base  = (size_t)E_SZ * B_SZ * 8;          // 4 MiB
    int*   cnt  = (int*)(ws + base);
    float* imp  = (float*)(ws + base + 64);
    int*   load = (int*)(ws + base + 128);

    hipMemsetAsync(ws + base, 0, 192, stream);             // cnt/imp/load = 0
    hipMemsetAsync(d_out, 0, (size_t)B_SZ * sizeof(float), stream);  // y = 0

    gate_kernel<<<1024, 256, 0, stream>>>(x, wg, bucket_row, bucket_gate, cnt, imp, load);
    expert_kernel<<<dim3(B_SZ / BM, E_SZ), 1024, 0, stream>>>(
        x, W1, b1, gamma, beta, W2, b2, bucket_row, bucket_gate, cnt, y);
    loss_kernel<<<1, 64, 0, stream>>>(imp, load, y + B_SZ);
}

// Round 2
// 2562.862 us; speedup vs baseline: 16.3685x; 16.3685x over previous
//
#include <hip/hip_runtime.h>
#include <math.h>

// MoE forward, MI355X. Round 2: bf16 MFMA expert GEMM, routed (sparse).
// B=32768 D=1200 E=16 H=1024 O=1 K=4.  d_out = [ y (32768 f32) | loss (1 f32) ]
//
// ws layout:
//   [0      , 2 MiB)   bucket_row  : int  [E][B]
//   [2 MiB  , 4 MiB)   bucket_gate : f32  [E][B]
//   [4 MiB +0)         cnt[16], +64 importance[16], +128 load[16]
//   [4 MiB +1 KiB)     Wp : bf16 [E][H][DP]  (W1 transposed, zero-padded)  ~38 MiB

#define B_SZ   32768
#define D_SZ   1200
#define DP     1216      // D padded to multiple of 32 (38 K-steps)
#define E_SZ   16
#define H_SZ   1024
#define LN_EPS 1e-5f
#define BM     64
#define KBLK   32

typedef __attribute__((ext_vector_type(8))) short  short8;
typedef __attribute__((ext_vector_type(4))) float  f32x4;

__device__ __forceinline__ unsigned short f2bf(float f) {   // RNE f32->bf16
    unsigned u = __float_as_uint(f);
    unsigned r = u + 0x7FFFu + ((u >> 16) & 1u);
    return (unsigned short)(r >> 16);
}

__device__ __forceinline__ void gload_lds16(const void* g, void* l) {
    __builtin_amdgcn_global_load_lds(
        (const __attribute__((address_space(1))) void*)g,
        (__attribute__((address_space(3))) void*)l, 16, 0, 0);
}

// ---------------------------------------------------------------- gating ----
__global__ __launch_bounds__(256)
void gate_kernel(const float* __restrict__ x, const float* __restrict__ wg,
                 int* __restrict__ bucket_row, float* __restrict__ bucket_gate,
                 int* __restrict__ cnt, float* __restrict__ importance,
                 int* __restrict__ load_cnt)
{
    __shared__ float s_imp[E_SZ];
    __shared__ int   s_load[E_SZ];
    if (threadIdx.x < E_SZ) { s_imp[threadIdx.x] = 0.f; s_load[threadIdx.x] = 0; }
    __syncthreads();

    const int lane  = threadIdx.x & 63;
    const int gwave = (int)((blockIdx.x * blockDim.x + threadIdx.x) >> 6);
    const int nwave = (int)((gridDim.x * blockDim.x) >> 6);

    for (int row = gwave; row < B_SZ; row += nwave) {
        float acc[E_SZ];
#pragma unroll
        for (int e = 0; e < E_SZ; ++e) acc[e] = 0.f;

        const float* xr = x + (size_t)row * D_SZ;
        for (int d = lane; d < D_SZ; d += 64) {
            const float xv = xr[d];
            const float4* w4 = (const float4*)(wg + (size_t)d * E_SZ);
            const float4 a = w4[0], b = w4[1], c = w4[2], dd = w4[3];
            acc[0]  += xv * a.x;  acc[1]  += xv * a.y;
            acc[2]  += xv * a.z;  acc[3]  += xv * a.w;
            acc[4]  += xv * b.x;  acc[5]  += xv * b.y;
            acc[6]  += xv * b.z;  acc[7]  += xv * b.w;
            acc[8]  += xv * c.x;  acc[9]  += xv * c.y;
            acc[10] += xv * c.z;  acc[11] += xv * c.w;
            acc[12] += xv * dd.x; acc[13] += xv * dd.y;
            acc[14] += xv * dd.z; acc[15] += xv * dd.w;
        }
#pragma unroll
        for (int e = 0; e < E_SZ; ++e) {
            float v = acc[e];
            v += __shfl_xor(v, 1);  v += __shfl_xor(v, 2);
            v += __shfl_xor(v, 4);  v += __shfl_xor(v, 8);
            v += __shfl_xor(v, 16); v += __shfl_xor(v, 32);
            acc[e] = v;
        }
        if (lane == 0) {
            float mx = acc[0];
#pragma unroll
            for (int e = 1; e < E_SZ; ++e) mx = fmaxf(mx, acc[e]);
            float p[E_SZ]; float s = 0.f;
#pragma unroll
            for (int e = 0; e < E_SZ; ++e) { p[e] = expf(acc[e] - mx); s += p[e]; }
            const float inv = 1.f / s;

            unsigned msk = 0; int idx[4]; float val[4]; float gsum = 0.f;
#pragma unroll
            for (int tsel = 0; tsel < 4; ++tsel) {
                float bv = -1.f; int bi = 0;
#pragma unroll
                for (int e = 0; e < E_SZ; ++e) {
                    const bool ok = !((msk >> e) & 1u) && (p[e] > bv);
                    bv = ok ? p[e] : bv; bi = ok ? e : bi;
                }
                msk |= 1u << bi;
                idx[tsel] = bi; val[tsel] = bv * inv; gsum += bv * inv;
            }
            const float denom = gsum + 1e-6f;
#pragma unroll
            for (int tsel = 0; tsel < 4; ++tsel) {
                const float g = val[tsel] / denom;
                const int e = idx[tsel];
                atomicAdd(&s_imp[e], g);
                atomicAdd(&s_load[e], 1);
                const int pos = atomicAdd(&cnt[e], 1);
                bucket_row[e * B_SZ + pos]  = row;
                bucket_gate[e * B_SZ + pos] = g;
            }
        }
    }
    __syncthreads();
    if (threadIdx.x < E_SZ) {
        atomicAdd(&importance[threadIdx.x], s_imp[threadIdx.x]);
        atomicAdd(&load_cnt[threadIdx.x], s_load[threadIdx.x]);
    }
}

// ------------------------------------------------------------------ loss ----
__global__ void loss_kernel(const float* __restrict__ imp,
                            const int* __restrict__ load_cnt,
                            float* __restrict__ loss_out)
{
    if (threadIdx.x == 0 && blockIdx.x == 0) {
        float mi = 0.f, ml = 0.f;
        for (int e = 0; e < E_SZ; ++e) { mi += imp[e]; ml += (float)load_cnt[e]; }
        mi *= (1.f / E_SZ); ml *= (1.f / E_SZ);
        float vi = 0.f, vl = 0.f;
        for (int e = 0; e < E_SZ; ++e) {
            const float di = imp[e] - mi;             vi += di * di;
            const float dl = (float)load_cnt[e] - ml; vl += dl * dl;
        }
        vi *= (1.f / (E_SZ - 1)); vl *= (1.f / (E_SZ - 1));
        *loss_out = 0.5f * (vi / (mi * mi + 1e-10f) + vl / (ml * ml + 1e-10f));
    }
}

// ------------------------------------------------ W1 transpose-pack (bf16) --
// W1 [E][D][H] f32  ->  Wp [E][H][DP] bf16, d>=D_SZ zero-padded.
__global__ __launch_bounds__(256)
void pack_w1(const float* __restrict__ W1, unsigned short* __restrict__ Wp)
{
    __shared__ float tile[32][33];
    const int e  = blockIdx.z;
    const int d0 = blockIdx.x * 32;
    const int h0 = blockIdx.y * 32;
    const int tx = threadIdx.x & 31, ty = threadIdx.x >> 5;   // ty 0..7

    const float* W1e = W1 + (size_t)e * D_SZ * H_SZ;
#pragma unroll
    for (int i = 0; i < 4; ++i) {
        const int d = d0 + ty + i * 8;
        tile[ty + i * 8][tx] = (d < D_SZ) ? W1e[(size_t)d * H_SZ + h0 + tx] : 0.f;
    }
    __syncthreads();
    unsigned short* WpE = Wp + (size_t)e * H_SZ * DP;
#pragma unroll
    for (int i = 0; i < 4; ++i) {
        const int h = h0 + ty + i * 8;
        WpE[(size_t)h * DP + d0 + tx] = f2bf(tile[tx][ty + i * 8]);
    }
}

// --------------------------------------------------- grouped expert pass ----
// grid (512, 16), 1024 threads (16 waves). Block: 64 gathered rows x H=1024.
// Wave w owns cols [w*64, w*64+64): 4 M-frags x 4 N-frags of 16x16 (16 mfma/K-step).
__global__ __launch_bounds__(1024, 4)
void expert_kernel(const float* __restrict__ x, const unsigned short* __restrict__ Wp,
                   const float* __restrict__ b1, const float* __restrict__ gamma,
                   const float* __restrict__ beta, const float* __restrict__ W2,
                   const float* __restrict__ b2,
                   const int* __restrict__ bucket_row,
                   const float* __restrict__ bucket_gate,
                   const int* __restrict__ cnt, float* __restrict__ y)
{
    const int e   = blockIdx.y;
    const int n_e = cnt[e];
    const int r0  = blockIdx.x * BM;
    if (r0 >= n_e) return;

    __shared__ unsigned short As[BM * KBLK];      // [row][k], 64B rows, 4 KiB
    __shared__ unsigned short Bs[H_SZ * KBLK];    // [n][k],   64B rows, 64 KiB
    __shared__ float red[16][BM][2];              // 8 KiB cross-wave reduce
    __shared__ float ln_m[BM], ln_r[BM];
    __shared__ int   srow[BM];
    __shared__ float sgate[BM];

    const int t   = threadIdx.x;
    const int w   = t >> 6;
    const int l   = t & 63;
    const int l15 = l & 15;
    const int lg  = l >> 4;

    if (t < BM) {
        const int i = r0 + t;
        srow[t]  = (i < n_e) ? bucket_row[e * B_SZ + i] : -1;
        sgate[t] = (i < n_e) ? bucket_gate[e * B_SZ + i] : 0.f;
    }
    __syncthreads();

    // staging roles
    const int ar = t >> 4;               // A: row 0..63
    const int ak = (t & 15) * 2;         // A: k-pair
    const int sr = srow[ar];
    const float* xrp = x + (size_t)(sr >= 0 ? sr : 0) * D_SZ;
    const unsigned short* WpE = Wp + (size_t)e * H_SZ * DP;
    const int bn0 = w * 64;
    const size_t bsrc_n = (size_t)(bn0 + (l >> 2)) * DP + (l & 3) * 8;

    f32x4 acc[16];
#pragma unroll
    for (int i = 0; i < 16; ++i) acc[i] = {0.f, 0.f, 0.f, 0.f};

    for (int kb = 0; kb < DP; kb += KBLK) {
        // stage A (f32 -> bf16) into LDS
        float2 xv;
        if (kb + ak < D_SZ) xv = *(const float2*)(xrp + kb + ak);
        else { xv.x = 0.f; xv.y = 0.f; }
        ushort2 uv; uv.x = f2bf(xv.x); uv.y = f2bf(xv.y);
        *(ushort2*)&As[ar * KBLK + ak] = uv;

        // stage B via async global->LDS (4 x 1KiB per wave)
#pragma unroll
        for (int i = 0; i < 4; ++i)
            gload_lds16(WpE + bsrc_n + (size_t)(i * 16) * DP + kb,
                        &Bs[(bn0 + i * 16) * KBLK]);
        __syncthreads();

        short8 af[4], bfr[4];
#pragma unroll
        for (int m = 0; m < 4; ++m)
            af[m] = *(const short8*)&As[(m * 16 + l15) * KBLK + lg * 8];
#pragma unroll
        for (int n = 0; n < 4; ++n)
            bfr[n] = *(const short8*)&Bs[(bn0 + n * 16 + l15) * KBLK + lg * 8];
#pragma unroll
        for (int m = 0; m < 4; ++m)
#pragma unroll
            for (int n = 0; n < 4; ++n)
                acc[m * 4 + n] = __builtin_amdgcn_mfma_f32_16x16x32_bf16(
                    af[m], bfr[n], acc[m * 4 + n], 0, 0, 0);
        __syncthreads();
    }

    // ---- epilogue: +b1, LN stats ----
    const float* b1e = b1    + (size_t)e * H_SZ;
    const float* gme = gamma + (size_t)e * H_SZ;
    const float* bte = beta  + (size_t)e * H_SZ;
    const float* w2e = W2    + (size_t)e * H_SZ;   // O==1

    float b1v[4];
#pragma unroll
    for (int n = 0; n < 4; ++n) b1v[n] = b1e[bn0 + n * 16 + l15];

#pragma unroll
    for (int m = 0; m < 4; ++m) {
        float s[4], q[4];
#pragma unroll
        for (int j = 0; j < 4; ++j) {
            float sv = 0.f, qv = 0.f;
#pragma unroll
            for (int n = 0; n < 4; ++n) {
                const float v = acc[m * 4 + n][j] + b1v[n];
                acc[m * 4 + n][j] = v;
                sv += v; qv += v * v;
            }
            s[j] = sv; q[j] = qv;
        }
#pragma unroll
        for (int j = 0; j < 4; ++j) {
#pragma unroll
            for (int d = 1; d < 16; d <<= 1) {
                s[j] += __shfl_xor(s[j], d);
                q[j] += __shfl_xor(q[j], d);
            }
        }
        if (l15 == 0) {
#pragma unroll
            for (int j = 0; j < 4; ++j) {
                const int row = m * 16 + lg * 4 + j;
                red[w][row][0] = s[j]; red[w][row][1] = q[j];
            }
        }
    }
    __syncthreads();

    if (t < BM) {
        float s = 0.f, q = 0.f;
#pragma unroll
        for (int ww = 0; ww < 16; ++ww) { s += red[ww][t][0]; q += red[ww][t][1]; }
        const float mean = s * (1.f / H_SZ);
        const float var  = q * (1.f / H_SZ) - mean * mean;
        ln_m[t] = mean;
        ln_r[t] = 1.f / sqrtf(var + LN_EPS);
    }
    __syncthreads();

    // ---- LN + relu + dot(W2) ----
    float gmv[4], btv[4], w2v[4];
#pragma unroll
    for (int n = 0; n < 4; ++n) {
        const int col = bn0 + n * 16 + l15;
        gmv[n] = gme[col]; btv[n] = bte[col]; w2v[n] = w2e[col];
    }
#pragma unroll
    for (int m = 0; m < 4; ++m) {
        float p[4];
#pragma unroll
        for (int j = 0; j < 4; ++j) {
            const int row = m * 16 + lg * 4 + j;
            const float mm = ln_m[row], rr = ln_r[row];
            float pv = 0.f;
#pragma unroll
            for (int n = 0; n < 4; ++n) {
                float h = (acc[m * 4 + n][j] - mm) * rr * gmv[n] + btv[n];
                h = fmaxf(h, 0.f);
                pv += h * w2v[n];
            }
            p[j] = pv;
        }
#pragma unroll
        for (int j = 0; j < 4; ++j)
#pragma unroll
            for (int d = 1; d < 16; d <<= 1) p[j] += __shfl_xor(p[j], d);
        if (l15 == 0) {
#pragma unroll
            for (int j = 0; j < 4; ++j) red[w][m * 16 + lg * 4 + j][0] = p[j];
        }
    }
    __syncthreads();

    if (t < BM && srow[t] >= 0) {
        float z = b2[e];
#pragma unroll
        for (int ww = 0; ww < 16; ++ww) z += red[ww][t][0];
        const float o = 1.f / (1.f + expf(-z));
        atomicAdd(&y[srow[t]], sgate[t] * o);
    }
}

// -------------------------------------------------------------- launcher ----
extern "C" void kernel_launch(void* const* d_in, const int* in_sizes, int n_in,
                              void* d_out, int out_size, void* d_ws, size_t ws_size,
                              hipStream_t stream)
{
    const float* x     = (const float*)d_in[0];
    const float* wg    = (const float*)d_in[1];
    const float* W1    = (const float*)d_in[2];
    const float* b1    = (const float*)d_in[3];
    const float* gamma = (const float*)d_in[4];
    const float* beta  = (const float*)d_in[5];
    const float* W2    = (const float*)d_in[6];
    const float* b2    = (const float*)d_in[7];
    float* y = (float*)d_out;

    char* ws = (char*)d_ws;
    int*   bucket_row  = (int*)ws;
    float* bucket_gate = (float*)(ws + (size_t)E_SZ * B_SZ * 4);
    const size_t base  = (size_t)E_SZ * B_SZ * 8;           // 4 MiB
    int*   cnt  = (int*)(ws + base);
    float* imp  = (float*)(ws + base + 64);
    int*   load = (int*)(ws + base + 128);
    unsigned short* Wp = (unsigned short*)(ws + base + 1024);

    hipMemsetAsync(ws + base, 0, 192, stream);
    hipMemsetAsync(d_out, 0, (size_t)B_SZ * sizeof(float), stream);

    pack_w1<<<dim3(DP / 32, H_SZ / 32, E_SZ), 256, 0, stream>>>(W1, Wp);
    gate_kernel<<<1024, 256, 0, stream>>>(x, wg, bucket_row, bucket_gate, cnt, imp, load);
    expert_kernel<<<dim3(B_SZ / BM, E_SZ), 1024, 0, stream>>>(
        x, Wp, b1, gamma, beta, W2, b2, bucket_row, bucket_gate, cnt, y);
    loss_kernel<<<1, 64, 0, stream>>>(imp, load, y + B_SZ);
}

// Round 4
// 1141.488 us; speedup vs baseline: 36.7504x; 2.2452x over previous
//
#include <hip/hip_runtime.h>
#include <math.h>

// MoE forward, MI355X. Round 3 (resubmit; R3 bench never ran - broker timeout).
// Deterministic gating (no contended atomics), swizzled LDS fragments,
// double-buffered expert K-loop.
// B=32768 D=1200 E=16 H=1024 O=1 K=4.  d_out = [ y (32768 f32) | loss (1 f32) ]
//
// ws layout:
//   [0      , 2 MiB)   bucket_row  : int  [E][B]
//   [2 MiB  , 4 MiB)   bucket_gate : f32  [E][B]
//   [4 MiB +0)         cnt[16], +64 importance[16], +128 load[16]
//   [4 MiB +1 KiB)     Wp : bf16 [E][H][DP]  (~38 MiB)   -- ALIASED before pack_w1 by
//                      gate scratch: tk_pack, gates4, lpos4, hist_g, bimp_g, base_g

#define B_SZ   32768
#define D_SZ   1200
#define DP     1216
#define E_SZ   16
#define H_SZ   1024
#define LN_EPS 1e-5f
#define BM     64
#define KBLK   32
#define NSTEP  (DP / KBLK)     // 38
#define NBG    512             // gate blocks
#define GR     64              // rows per gate block

typedef __attribute__((ext_vector_type(8))) short  short8;
typedef __attribute__((ext_vector_type(4))) float  f32x4;

__device__ __forceinline__ unsigned short f2bf(float f) {   // RNE f32->bf16
    unsigned u = __float_as_uint(f);
    unsigned r = u + 0x7FFFu + ((u >> 16) & 1u);
    return (unsigned short)(r >> 16);
}

__device__ __forceinline__ void gload_lds16(const void* g, void* l) {
    __builtin_amdgcn_global_load_lds(
        (const __attribute__((address_space(1))) void*)g,
        (__attribute__((address_space(3))) void*)l, 16, 0, 0);
}

// ------------------------------------------------------- gate A: logits ----
__global__ __launch_bounds__(256)
void gate_a(const float* __restrict__ x, const float* __restrict__ wg,
            unsigned* __restrict__ tk_pack, float* __restrict__ gates4,
            unsigned short* __restrict__ lpos4,
            unsigned* __restrict__ hist_g, float* __restrict__ bimp_g)
{
    __shared__ int   hist[E_SZ];
    __shared__ float bimp[E_SZ];
    if (threadIdx.x < E_SZ) { hist[threadIdx.x] = 0; bimp[threadIdx.x] = 0.f; }
    __syncthreads();

    const int lane = threadIdx.x & 63;
    const int w    = threadIdx.x >> 6;        // 0..3
    const int rb   = blockIdx.x * GR;

    for (int it = 0; it < GR / 4; ++it) {
        const int row = rb + it * 4 + w;
        float acc[E_SZ];
#pragma unroll
        for (int e = 0; e < E_SZ; ++e) acc[e] = 0.f;

        const float* xr = x + (size_t)row * D_SZ;
        for (int d = lane; d < D_SZ; d += 64) {           // same order as R2 ->
            const float xv = xr[d];                       // identical logits
            const float4* w4 = (const float4*)(wg + (size_t)d * E_SZ);
            const float4 a = w4[0], b = w4[1], c = w4[2], dd = w4[3];
            acc[0]  += xv * a.x;  acc[1]  += xv * a.y;
            acc[2]  += xv * a.z;  acc[3]  += xv * a.w;
            acc[4]  += xv * b.x;  acc[5]  += xv * b.y;
            acc[6]  += xv * b.z;  acc[7]  += xv * b.w;
            acc[8]  += xv * c.x;  acc[9]  += xv * c.y;
            acc[10] += xv * c.z;  acc[11] += xv * c.w;
            acc[12] += xv * dd.x; acc[13] += xv * dd.y;
            acc[14] += xv * dd.z; acc[15] += xv * dd.w;
        }
#pragma unroll
        for (int e = 0; e < E_SZ; ++e) {
            float v = acc[e];
            v += __shfl_xor(v, 1);  v += __shfl_xor(v, 2);
            v += __shfl_xor(v, 4);  v += __shfl_xor(v, 8);
            v += __shfl_xor(v, 16); v += __shfl_xor(v, 32);
            acc[e] = v;
        }
        if (lane == 0) {
            float mx = acc[0];
#pragma unroll
            for (int e = 1; e < E_SZ; ++e) mx = fmaxf(mx, acc[e]);
            float p[E_SZ]; float s = 0.f;
#pragma unroll
            for (int e = 0; e < E_SZ; ++e) { p[e] = expf(acc[e] - mx); s += p[e]; }
            const float inv = 1.f / s;

            unsigned msk = 0; int idx[4]; float val[4]; float gsum = 0.f;
#pragma unroll
            for (int tsel = 0; tsel < 4; ++tsel) {
                float bv = -1.f; int bi = 0;
#pragma unroll
                for (int e = 0; e < E_SZ; ++e) {
                    const bool ok = !((msk >> e) & 1u) && (p[e] > bv);
                    bv = ok ? p[e] : bv; bi = ok ? e : bi;
                }
                msk |= 1u << bi;
                idx[tsel] = bi; val[tsel] = bv * inv; gsum += bv * inv;
            }
            const float denom = gsum + 1e-6f;
            unsigned tkp = 0;
#pragma unroll
            for (int tsel = 0; tsel < 4; ++tsel) {
                const float g = val[tsel] / denom;
                const int e = idx[tsel];
                const int lp = atomicAdd(&hist[e], 1);    // LDS atomic: fast
                atomicAdd(&bimp[e], g);
                tkp |= (unsigned)e << (8 * tsel);
                gates4[row * 4 + tsel] = g;
                lpos4[row * 4 + tsel]  = (unsigned short)lp;
            }
            tk_pack[row] = tkp;
        }
    }
    __syncthreads();
    if (threadIdx.x < E_SZ) {
        hist_g[blockIdx.x * E_SZ + threadIdx.x] = (unsigned)hist[threadIdx.x];
        bimp_g[blockIdx.x * E_SZ + threadIdx.x] = bimp[threadIdx.x];
    }
}

// ------------------------------------- gate B: prefix scan + cnt + loss ----
__global__ void gate_b(const unsigned* __restrict__ hist_g, const float* __restrict__ bimp_g,
                       unsigned* __restrict__ base_g, int* __restrict__ cnt,
                       float* __restrict__ imp, int* __restrict__ loadc,
                       float* __restrict__ loss_out)
{
    __shared__ float s_i[E_SZ], s_c[E_SZ];
    const int t = threadIdx.x;
    if (t < E_SZ) {
        unsigned run = 0; float ri = 0.f;
#pragma unroll 8
        for (int b = 0; b < NBG; ++b) {
            base_g[b * E_SZ + t] = run;
            run += hist_g[b * E_SZ + t];
            ri  += bimp_g[b * E_SZ + t];
        }
        cnt[t] = (int)run; imp[t] = ri; loadc[t] = (int)run;
        s_i[t] = ri; s_c[t] = (float)run;
    }
    __syncthreads();
    if (t == 0) {
        float mi = 0.f, ml = 0.f;
        for (int e = 0; e < E_SZ; ++e) { mi += s_i[e]; ml += s_c[e]; }
        mi *= (1.f / E_SZ); ml *= (1.f / E_SZ);
        float vi = 0.f, vl = 0.f;
        for (int e = 0; e < E_SZ; ++e) {
            const float di = s_i[e] - mi; vi += di * di;
            const float dl = s_c[e] - ml; vl += dl * dl;
        }
        vi *= (1.f / (E_SZ - 1)); vl *= (1.f / (E_SZ - 1));
        *loss_out = 0.5f * (vi / (mi * mi + 1e-10f) + vl / (ml * ml + 1e-10f));
    }
}

// ------------------------------------------------- gate C: bucket scatter ---
__global__ __launch_bounds__(256)
void gate_c(const unsigned* __restrict__ tk_pack, const float* __restrict__ gates4,
            const unsigned short* __restrict__ lpos4, const unsigned* __restrict__ base_g,
            int* __restrict__ bucket_row, float* __restrict__ bucket_gate)
{
    const int t   = threadIdx.x;
    const int row = blockIdx.x * GR + (t >> 2);
    const int j   = t & 3;
    const unsigned tkp = tk_pack[row];
    const int e = (int)((tkp >> (8 * j)) & 0xffu);
    const unsigned dst = base_g[blockIdx.x * E_SZ + e] + (unsigned)lpos4[row * 4 + j];
    bucket_row[e * B_SZ + dst]  = row;
    bucket_gate[e * B_SZ + dst] = gates4[row * 4 + j];
}

// ------------------------------------------------ W1 transpose-pack (bf16) --
__global__ __launch_bounds__(256)
void pack_w1(const float* __restrict__ W1, unsigned short* __restrict__ Wp)
{
    __shared__ float tile[32][33];
    const int e  = blockIdx.z;
    const int d0 = blockIdx.x * 32;
    const int h0 = blockIdx.y * 32;
    const int tx = threadIdx.x & 31, ty = threadIdx.x >> 5;

    const float* W1e = W1 + (size_t)e * D_SZ * H_SZ;
#pragma unroll
    for (int i = 0; i < 4; ++i) {
        const int d = d0 + ty + i * 8;
        tile[ty + i * 8][tx] = (d < D_SZ) ? W1e[(size_t)d * H_SZ + h0 + tx] : 0.f;
    }
    __syncthreads();
    unsigned short* WpE = Wp + (size_t)e * H_SZ * DP;
#pragma unroll
    for (int i = 0; i < 4; ++i) {
        const int h = h0 + ty + i * 8;
        WpE[(size_t)h * DP + d0 + tx] = f2bf(tile[tx][ty + i * 8]);
    }
}

// --------------------------------------------------- grouped expert pass ----
// grid (512, 16), 1024 threads (16 waves). Block: 64 gathered rows x H=1024.
// Double-buffered LDS; granule-XOR swizzle g ^= (row>>1)&3 on 16B granules.
__global__ __launch_bounds__(1024, 4)
void expert_kernel(const float* __restrict__ x, const unsigned short* __restrict__ Wp,
                   const float* __restrict__ b1, const float* __restrict__ gamma,
                   const float* __restrict__ beta, const float* __restrict__ W2,
                   const float* __restrict__ b2,
                   const int* __restrict__ bucket_row,
                   const float* __restrict__ bucket_gate,
                   const int* __restrict__ cnt, float* __restrict__ y)
{
    const int e   = blockIdx.y;
    const int n_e = cnt[e];
    const int r0  = blockIdx.x * BM;
    if (r0 >= n_e) return;

    __shared__ unsigned short As[2][BM * KBLK];      // 2 x 4 KiB
    __shared__ unsigned short Bs[2][H_SZ * KBLK];    // 2 x 64 KiB
    __shared__ float red[16][BM][2];                 // 8 KiB
    __shared__ float ln_m[BM], ln_r[BM];
    __shared__ int   srow[BM];
    __shared__ float sgate[BM];

    const int t   = threadIdx.x;
    const int w   = t >> 6;
    const int l   = t & 63;
    const int l15 = l & 15;
    const int lg  = l >> 4;
    const int sw  = (l15 >> 1) & 3;                  // read-side granule XOR

    if (t < BM) {
        const int i = r0 + t;
        srow[t]  = (i < n_e) ? bucket_row[e * B_SZ + i] : -1;
        sgate[t] = (i < n_e) ? bucket_gate[e * B_SZ + i] : 0.f;
    }
    __syncthreads();

    // A staging role: thread t writes elements (2*(t&15), +1) of row t>>4
    const int ar = t >> 4;
    const int ai = t & 15;
    const int ak = ai * 2;
    const int abyte = ar * 64 + ((ai & 3) << 2) + ((((ai >> 2) ^ ((ar >> 1) & 3)) & 3) << 4);
    const int sr = srow[ar];
    const float* xrp = x + (size_t)(sr >= 0 ? sr : 0) * D_SZ;

    // B staging role: per wave, 4 x gload_lds of 1 KiB; source granule pre-swizzled
    const unsigned short* WpE = Wp + (size_t)e * H_SZ * DP;
    const int bn0 = w * 64;
    const size_t bsrc = (size_t)(bn0 + (l >> 2)) * DP + (size_t)(((l & 3) ^ ((l >> 3) & 3)) * 8);

    f32x4 acc[16];
#pragma unroll
    for (int i = 0; i < 16; ++i) acc[i] = {0.f, 0.f, 0.f, 0.f};

    // ---- prologue: stage step 0 into buffer 0
    {
        float2 x0 = *(const float2*)(xrp + ak);      // ak<=30 < D_SZ
        ushort2 uv; uv.x = f2bf(x0.x); uv.y = f2bf(x0.y);
        *(ushort2*)((char*)&As[0][0] + abyte) = uv;
        unsigned short* Bn = &Bs[0][0];
#pragma unroll
        for (int i = 0; i < 4; ++i)
            gload_lds16(WpE + bsrc + (size_t)(i * 16) * DP, Bn + (bn0 + i * 16) * KBLK);
    }
    __syncthreads();

    int cur = 0;
    for (int step = 0; step < NSTEP; ++step) {
        const int  nxt  = cur ^ 1;
        const bool more = (step + 1) < NSTEP;
        float2 xn = {0.f, 0.f};
        if (more) {
            const int kk = (step + 1) * KBLK;
            if (kk + ak < D_SZ) xn = *(const float2*)(xrp + kk + ak);
            unsigned short* Bn = &Bs[nxt][0];
#pragma unroll
            for (int i = 0; i < 4; ++i)
                gload_lds16(WpE + bsrc + (size_t)(i * 16) * DP + kk,
                            Bn + (bn0 + i * 16) * KBLK);
        }
        // ---- compute on buffer cur
        const char* Ac = (const char*)&As[cur][0];
        const char* Bc = (const char*)&Bs[cur][0];
        short8 af[4], bfr[4];
#pragma unroll
        for (int m = 0; m < 4; ++m)
            af[m] = *(const short8*)(Ac + (m * 16 + l15) * 64 + ((lg ^ sw) << 4));
#pragma unroll
        for (int n = 0; n < 4; ++n)
            bfr[n] = *(const short8*)(Bc + (size_t)(bn0 + n * 16 + l15) * 64 + ((lg ^ sw) << 4));
#pragma unroll
        for (int m = 0; m < 4; ++m)
#pragma unroll
            for (int n = 0; n < 4; ++n)
                acc[m * 4 + n] = __builtin_amdgcn_mfma_f32_16x16x32_bf16(
                    af[m], bfr[n], acc[m * 4 + n], 0, 0, 0);
        if (more) {
            ushort2 uv; uv.x = f2bf(xn.x); uv.y = f2bf(xn.y);
            *(ushort2*)((char*)&As[nxt][0] + abyte) = uv;
        }
        __syncthreads();                             // drains vmcnt+lgkmcnt
        cur = nxt;
    }

    // ---- epilogue: +b1, LN stats ----
    const float* b1e = b1    + (size_t)e * H_SZ;
    const float* gme = gamma + (size_t)e * H_SZ;
    const float* bte = beta  + (size_t)e * H_SZ;
    const float* w2e = W2    + (size_t)e * H_SZ;     // O==1

    float b1v[4];
#pragma unroll
    for (int n = 0; n < 4; ++n) b1v[n] = b1e[bn0 + n * 16 + l15];

#pragma unroll
    for (int m = 0; m < 4; ++m) {
        float s[4], q[4];
#pragma unroll
        for (int j = 0; j < 4; ++j) {
            float sv = 0.f, qv = 0.f;
#pragma unroll
            for (int n = 0; n < 4; ++n) {
                const float v = acc[m * 4 + n][j] + b1v[n];
                acc[m * 4 + n][j] = v;
                sv += v; qv += v * v;
            }
            s[j] = sv; q[j] = qv;
        }
#pragma unroll
        for (int j = 0; j < 4; ++j) {
#pragma unroll
            for (int d = 1; d < 16; d <<= 1) {
                s[j] += __shfl_xor(s[j], d);
                q[j] += __shfl_xor(q[j], d);
            }
        }
        if (l15 == 0) {
#pragma unroll
            for (int j = 0; j < 4; ++j) {
                const int row = m * 16 + lg * 4 + j;
                red[w][row][0] = s[j]; red[w][row][1] = q[j];
            }
        }
    }
    __syncthreads();

    if (t < BM) {
        float s = 0.f, q = 0.f;
#pragma unroll
        for (int ww = 0; ww < 16; ++ww) { s += red[ww][t][0]; q += red[ww][t][1]; }
        const float mean = s * (1.f / H_SZ);
        const float var  = q * (1.f / H_SZ) - mean * mean;
        ln_m[t] = mean;
        ln_r[t] = 1.f / sqrtf(var + LN_EPS);
    }
    __syncthreads();

    float gmv[4], btv[4], w2v[4];
#pragma unroll
    for (int n = 0; n < 4; ++n) {
        const int col = bn0 + n * 16 + l15;
        gmv[n] = gme[col]; btv[n] = bte[col]; w2v[n] = w2e[col];
    }
#pragma unroll
    for (int m = 0; m < 4; ++m) {
        float p[4];
#pragma unroll
        for (int j = 0; j < 4; ++j) {
            const int row = m * 16 + lg * 4 + j;
            const float mm = ln_m[row], rr = ln_r[row];
            float pv = 0.f;
#pragma unroll
            for (int n = 0; n < 4; ++n) {
                float h = (acc[m * 4 + n][j] - mm) * rr * gmv[n] + btv[n];
                h = fmaxf(h, 0.f);
                pv += h * w2v[n];
            }
            p[j] = pv;
        }
#pragma unroll
        for (int j = 0; j < 4; ++j)
#pragma unroll
            for (int d = 1; d < 16; d <<= 1) p[j] += __shfl_xor(p[j], d);
        if (l15 == 0) {
#pragma unroll
            for (int j = 0; j < 4; ++j) red[w][m * 16 + lg * 4 + j][0] = p[j];
        }
    }
    __syncthreads();

    if (t < BM && srow[t] >= 0) {
        float z = b2[e];
#pragma unroll
        for (int ww = 0; ww < 16; ++ww) z += red[ww][t][0];
        const float o = 1.f / (1.f + expf(-z));
        atomicAdd(&y[srow[t]], sgate[t] * o);
    }
}

// -------------------------------------------------------------- launcher ----
extern "C" void kernel_launch(void* const* d_in, const int* in_sizes, int n_in,
                              void* d_out, int out_size, void* d_ws, size_t ws_size,
                              hipStream_t stream)
{
    const float* x     = (const float*)d_in[0];
    const float* wg    = (const float*)d_in[1];
    const float* W1    = (const float*)d_in[2];
    const float* b1    = (const float*)d_in[3];
    const float* gamma = (const float*)d_in[4];
    const float* beta  = (const float*)d_in[5];
    const float* W2    = (const float*)d_in[6];
    const float* b2    = (const float*)d_in[7];
    float* y = (float*)d_out;

    char* ws = (char*)d_ws;
    int*   bucket_row  = (int*)ws;
    float* bucket_gate = (float*)(ws + (size_t)E_SZ * B_SZ * 4);
    const size_t base  = (size_t)E_SZ * B_SZ * 8;           // 4 MiB
    int*   cnt  = (int*)(ws + base);
    float* imp  = (float*)(ws + base + 64);
    int*   load = (int*)(ws + base + 128);
    unsigned short* Wp = (unsigned short*)(ws + base + 1024);

    // gate scratch ALIASES the Wp region (all gate kernels run before pack_w1)
    char* g = ws + base + 1024;
    unsigned*       tk_pack = (unsigned*)g;                            // 128 KiB
    float*          gates4  = (float*)(g + (size_t)B_SZ * 4);          // 512 KiB
    unsigned short* lpos4   = (unsigned short*)(g + (size_t)B_SZ * 20);// 256 KiB
    unsigned*       hist_g  = (unsigned*)(g + (size_t)B_SZ * 28);      // 32 KiB
    float*          bimp_g  = (float*)(g + (size_t)B_SZ * 28 + NBG * E_SZ * 4);
    unsigned*       base_g  = (unsigned*)(g + (size_t)B_SZ * 28 + NBG * E_SZ * 8);

    hipMemsetAsync(d_out, 0, (size_t)B_SZ * sizeof(float), stream);    // y = 0

    gate_a<<<NBG, 256, 0, stream>>>(x, wg, tk_pack, gates4, lpos4, hist_g, bimp_g);
    gate_b<<<1, 64, 0, stream>>>(hist_g, bimp_g, base_g, cnt, imp, load, y + B_SZ);
    gate_c<<<NBG, 256, 0, stream>>>(tk_pack, gates4, lpos4, base_g, bucket_row, bucket_gate);
    pack_w1<<<dim3(DP / 32, H_SZ / 32, E_SZ), 256, 0, stream>>>(W1, Wp);
    expert_kernel<<<dim3(B_SZ / BM, E_SZ), 1024, 0, stream>>>(
        x, Wp, b1, gamma, beta, W2, b2, bucket_row, bucket_gate, cnt, y);
}